// Round 8
// baseline (358.429 us; speedup 1.0000x reference)
//
#include <hip/hip_runtime.h>

#define BB 4
#define NN 2048
#define DD 256
#define NPAIR 16
#define GCX 40                    // 640/16 cells in x
#define GCY 30                    // 480/16 cells in y
#define NCELL (GCX * GCY)         // 1200
#define TILE_S 32                 // src points per block
#define NTIL (NN / TILE_S)        // 64
#define NBLK (NPAIR * NTIL)       // 1024 blocks = exactly 4/CU
#define WQ_CAP 128                // per-wave hit queue (lambda ~11, +36 sigma)

// Poison-proof record tags (protocol HW-proven rounds 2/6, absmax 0.0):
// constant fill P can't satisfy P==KEY1^bid AND P==KEY2^bid (KEY1!=KEY2).
#define KEY1 0xA5C3E7D1u
#define KEY2 0x3B9ACA07u

__device__ __forceinline__ int cell_clamp(int v, int hi) {
    return v < 0 ? 0 : (v > hi ? hi : v);
}

// ONE dispatch, HIGH occupancy: R6's verified fused structure at 4 blocks/CU.
// Block = (pair, src-tile of 32). 1024 blocks, 16 waves/CU resident.
//  * Per-block LDS counting sort of the pair's 2048 dst points (verbatim the
//    absmax-0.0 R5/R6 build math; x64 redundant but wall-clock parallel).
//  * Walk: 8 threads per src point, stride-8 over each contiguous cell-row
//    range of the 3x3 neighborhood (cells >=2 apart are >8px, exact on
//    denormed floats => candidate superset; d2 test bit-identical => same
//    hit set as the verified brute force).
//  * Tail gather at 16 waves/CU (4x the latency hiding of slow R6).
//  * Last-arriver finalize: tagged 16B record/block, ONE non-spinning read
//    pass (4 records/thread); all-valid => fixed-order reduction -> out.
__global__ __launch_bounds__(256, 4) void fused_kernel(const float* __restrict__ feat,
                                                       const float* __restrict__ pts_src,
                                                       const float* __restrict__ pts_dst,
                                                       const int* __restrict__ hptr,
                                                       const int* __restrict__ wptr,
                                                       unsigned int* __restrict__ recs,
                                                       float* __restrict__ out) {
    __shared__ float2 bpts[NN];                          // 16 KB denormed dst pts
    __shared__ unsigned short bmid[NN];                  // 4 KB original m index
    __shared__ int st[NCELL + 1];                        // cell starts + sentinel
    __shared__ int cur[NCELL];                           // counts -> cursors
    __shared__ int tsum[256];                            // prefix scratch
    __shared__ unsigned int wq[4][WQ_CAP];               // per-wave hit queues
    __shared__ unsigned int wqc[4];
    __shared__ float bsum[4];
    __shared__ unsigned int bcnt[4];
    __shared__ float rs[4], rc[4];                       // reducer cross-wave

    const int xcd  = blockIdx.x & 7;                     // round-robin -> XCD
    const int rest = blockIdx.x >> 3;                    // 0..127
    const int pair = (xcd << 1) | (rest >> 6);           // 2 pairs/XCD
    const int tile = rest & 63;                          // 0..63
    const int i = pair >> 2;
    const int j = pair & 3;
    const float sx = ((float)(*wptr) - 1.0f) * 0.5f;
    const float sy = ((float)(*hptr) - 1.0f) * 0.5f;

    const int wave = threadIdx.x >> 6;
    const int lane = threadIdx.x & 63;
    if (lane == 0) wqc[wave] = 0u;                       // same-wave order: no barrier

    // ---- per-block LDS counting sort of this pair's 2048 dst points ----
    for (int t = threadIdx.x; t < NCELL; t += 256) cur[t] = 0;
    __syncthreads();

    const float2* pd = (const float2*)(pts_dst + (size_t)pair * NN * 2);
    float qx[8], qy[8]; int qc[8];
#pragma unroll
    for (int k = 0; k < 8; ++k) {
        const float2 r = pd[threadIdx.x + k * 256];
        qx[k] = fmaf(r.x, sx, sx);                       // exact same denorm form
        qy[k] = fmaf(r.y, sy, sy);
        const int cx = cell_clamp((int)(qx[k] * 0.0625f), GCX - 1);
        const int cy = cell_clamp((int)(qy[k] * 0.0625f), GCY - 1);
        qc[k] = cx + GCX * cy;
        atomicAdd(&cur[qc[k]], 1);
    }
    __syncthreads();

    // exclusive prefix over 1200 cells: 5/thread + Hillis-Steele over 256
    const int base = threadIdx.x * 5;
    int loc[5]; int s = 0;
#pragma unroll
    for (int k = 0; k < 5; ++k) {
        const int c = base + k;
        const int v = (c < NCELL) ? cur[c] : 0;
        loc[k] = s; s += v;
    }
    tsum[threadIdx.x] = s;
    __syncthreads();
    for (int off = 1; off < 256; off <<= 1) {
        const int v = (threadIdx.x >= off) ? tsum[threadIdx.x - off] : 0;
        __syncthreads();
        tsum[threadIdx.x] += v;
        __syncthreads();
    }
    const int tbase = tsum[threadIdx.x] - s;             // exclusive thread base
#pragma unroll
    for (int k = 0; k < 5; ++k) {
        const int c = base + k;
        if (c < NCELL) st[c] = tbase + loc[k];
    }
    if (threadIdx.x == 0) st[NCELL] = NN;                // sentinel end
    __syncthreads();
    for (int t = threadIdx.x; t < NCELL; t += 256) cur[t] = st[t];
    __syncthreads();
#pragma unroll
    for (int k = 0; k < 8; ++k) {
        const int pos = atomicAdd(&cur[qc[k]], 1);       // pos < NN by construction
        bpts[pos] = make_float2(qx[k], qy[k]);
        bmid[pos] = (unsigned short)(threadIdx.x + k * 256);
    }

    // ---- src point: 8 threads/src, stride-8 over each row range ----
    const int sub = threadIdx.x & 7;                     // candidate sublane
    const int sl  = threadIdx.x >> 3;                    // 0..31 local src id
    const int n   = tile * TILE_S + sl;
    const float2 r = ((const float2*)pts_src)[(size_t)i * NN + n];
    const float px = fmaf(r.x, sx, sx);
    const float py = fmaf(r.y, sy, sy);
    const int cxs = cell_clamp((int)(px * 0.0625f), GCX - 1);
    const int cys = cell_clamp((int)(py * 0.0625f), GCY - 1);
    const int cxlo = cxs > 0 ? cxs - 1 : 0;
    const int cxhi = cxs < GCX - 1 ? cxs + 1 : GCX - 1;
    __syncthreads();                                     // bins ready

#pragma unroll
    for (int dy = -1; dy <= 1; ++dy) {
        const int cy2 = cys + dy;
        if ((unsigned)cy2 >= (unsigned)GCY) continue;
        const int b0 = st[cy2 * GCX + cxlo];
        const int e0 = st[cy2 * GCX + cxhi + 1];
        for (int idx = b0 + sub; idx < e0; idx += 8) {
            const float2 q = bpts[idx];
            const float ax = px - q.x, ay = py - q.y;
            if (fmaf(ax, ax, ay * ay) <= 64.0f) {        // identical d2 test
                const unsigned int s2 = atomicAdd(&wqc[wave], 1u);
                if (s2 < WQ_CAP) wq[wave][s2] = ((unsigned int)sl << 11) | (unsigned int)idx;
            }
        }
    }

    // ---- tail: 8 hits at a time, 8 lanes/hit; dot + both norms fused ----
    const unsigned int hc = min(wqc[wave], (unsigned int)WQ_CAP);
    const int g = lane >> 3, sb = lane & 7;
    float lsum = 0.0f;
    for (unsigned int h0 = 0; h0 < hc; h0 += 8) {
        const unsigned int hid = h0 + (unsigned int)g;
        const bool valid = hid < hc;
        float dd = 0.0f, aa = 0.0f, bb = 0.0f;
        if (valid) {
            const unsigned int rec = wq[wave][hid];
            const int m = (int)bmid[rec & 2047u];
            const int nn2 = tile * TILE_S + (int)(rec >> 11);
            const float4* pa = (const float4*)(feat + (size_t)(j * NN + nn2) * DD);
            const float4* pb = (const float4*)(feat + (size_t)(i * NN + m) * DD);
#pragma unroll
            for (int t = 0; t < 8; ++t) {
                const float4 a = pa[t * 8 + sb];
                const float4 b = pb[t * 8 + sb];
                dd = fmaf(a.x, b.x, fmaf(a.y, b.y, fmaf(a.z, b.z, fmaf(a.w, b.w, dd))));
                aa = fmaf(a.x, a.x, fmaf(a.y, a.y, fmaf(a.z, a.z, fmaf(a.w, a.w, aa))));
                bb = fmaf(b.x, b.x, fmaf(b.y, b.y, fmaf(b.z, b.z, fmaf(b.w, b.w, bb))));
            }
        }
        dd += __shfl_xor(dd, 1, 64);  aa += __shfl_xor(aa, 1, 64);  bb += __shfl_xor(bb, 1, 64);
        dd += __shfl_xor(dd, 2, 64);  aa += __shfl_xor(aa, 2, 64);  bb += __shfl_xor(bb, 2, 64);
        dd += __shfl_xor(dd, 4, 64);  aa += __shfl_xor(aa, 4, 64);  bb += __shfl_xor(bb, 4, 64);
        if (valid && sb == 0) {
            const float p = aa * bb;                     // (|fa|*|fb|)^2 >> eps^2
            float rr = rsqrtf(p);
            rr = rr * (1.5f - 0.5f * p * rr * rr);       // one Newton step
            lsum += 1.0f - dd * rr;
        }
    }
#pragma unroll
    for (int off = 32; off >= 1; off >>= 1) lsum += __shfl_xor(lsum, off, 64);

    // ---- block partial -> tagged record ----
    if (lane == 0) { bsum[wave] = lsum; bcnt[wave] = hc; }
    __syncthreads();
    if (threadIdx.x == 0) {
        const float S = bsum[0] + bsum[1] + bsum[2] + bsum[3];
        const unsigned int C = bcnt[0] + bcnt[1] + bcnt[2] + bcnt[3];
        unsigned int* rec = recs + 4u * blockIdx.x;
        __hip_atomic_store(rec + 0, __float_as_uint(S), __ATOMIC_RELAXED, __HIP_MEMORY_SCOPE_AGENT);
        __hip_atomic_store(rec + 1, C,                  __ATOMIC_RELAXED, __HIP_MEMORY_SCOPE_AGENT);
        __hip_atomic_store(rec + 2, KEY1 ^ (unsigned)blockIdx.x, __ATOMIC_RELEASE, __HIP_MEMORY_SCOPE_AGENT);
        __hip_atomic_store(rec + 3, KEY2 ^ (unsigned)blockIdx.x, __ATOMIC_RELEASE, __HIP_MEMORY_SCOPE_AGENT);
        __threadfence();
    }
    __syncthreads();

    // ---- last-arriver finalize: ONE read pass (4 records/thread), no spin ----
    float fs = 0.0f, fc = 0.0f; int ok = 1;
#pragma unroll
    for (int k = 0; k < 4; ++k) {                        // fixed order: deterministic
        const unsigned int t = (unsigned int)threadIdx.x + 256u * k;
        unsigned int* rrec = recs + 4u * t;
        const unsigned int w2 = __hip_atomic_load(rrec + 2, __ATOMIC_ACQUIRE, __HIP_MEMORY_SCOPE_AGENT);
        const unsigned int w3 = __hip_atomic_load(rrec + 3, __ATOMIC_ACQUIRE, __HIP_MEMORY_SCOPE_AGENT);
        ok &= (w2 == (KEY1 ^ t)) && (w3 == (KEY2 ^ t));
        fs += __uint_as_float(__hip_atomic_load(rrec + 0, __ATOMIC_RELAXED, __HIP_MEMORY_SCOPE_AGENT));
        fc += (float)__hip_atomic_load(rrec + 1, __ATOMIC_RELAXED, __HIP_MEMORY_SCOPE_AGENT);
    }
    if (__syncthreads_and(ok)) {
        // all 1024 records valid: this block is (one of) the last finishers.
        // Fixed-order reduction -> bitwise-identical result whichever block
        // computes it; duplicate out-writes are benign.
#pragma unroll
        for (int off = 32; off >= 1; off >>= 1) {
            fs += __shfl_xor(fs, off, 64);
            fc += __shfl_xor(fc, off, 64);
        }
        if (lane == 0) { rs[wave] = fs; rc[wave] = fc; }
        __syncthreads();
        if (threadIdx.x == 0) {
            const float S = rs[0] + rs[1] + rs[2] + rs[3];
            const float C = rc[0] + rc[1] + rc[2] + rc[3];
            out[0] = S / fmaxf(C, 1.0f);                 // max(cnt, 1)
        }
    }
}

extern "C" void kernel_launch(void* const* d_in, const int* in_sizes, int n_in,
                              void* d_out, int out_size, void* d_ws, size_t ws_size,
                              hipStream_t stream) {
    const float* feat    = (const float*)d_in[0];   // [B,N,D] f32
    const float* pts_src = (const float*)d_in[1];   // [B,N,2] f32
    const float* pts_dst = (const float*)d_in[2];   // [B,B,N,2] f32
    // d_in[3] = invis_idx — unused by the reference
    const int* hptr = (const int*)d_in[4];          // height (scalar)
    const int* wptr = (const int*)d_in[5];          // width  (scalar)
    float* out = (float*)d_out;

    unsigned int* recs = (unsigned int*)d_ws;       // 1024 x 16 B = 16 KB

    fused_kernel<<<NBLK, 256, 0, stream>>>(feat, pts_src, pts_dst,
                                           hptr, wptr, recs, out);
}

// Round 9
// 86.434 us; speedup vs baseline: 4.1469x; 4.1469x over previous
//
#include <hip/hip_runtime.h>

#define BB 4
#define NN 2048
#define DD 256
#define TILE_N 32                 // n per block
#define NPW 8                     // n per wave (4 waves * 8 = 32)
#define NT (NN / TILE_N)          // 64 n-tiles
#define MSPLIT 2                  // m-range halves
#define MLEN (NN / MSPLIT)        // 1024 m per block
#define MCH (MLEN / 128)          // 8 chunks of 128 m (2 points/lane)
#define WQ_CAP 96                 // per-wave hit queue (lambda ~5.4)
#define NBLK (BB * BB * NT * MSPLIT)   // 2048 blocks = 8/CU, all co-resident

// Kernel 1: block = (pair, n-tile of 32, m-half of 1024).
// NO LDS staging, NO __syncthreads before the scan: each lane reads its
// chunk's points directly from global (L2-resident, prefetched 1 chunk
// ahead, denorm on the fly). Per-wave chain ~3K cycles; full grid
// co-resident. Hits -> per-wave LDS queue; tail: 16 hits in parallel
// (4 lanes/hit) with dot + both norms fused. Partials to private slots.
// SESSION VERDICT (9 rounds): this structure at 8 blocks/CU is the
// empirical optimum. Beaten by nothing: LDS staging (R3), occupancy
// changes (R1/R3), spatial binning in 3 deployments (R5/R7: dispatch
// gaps + cold caches; R6/R8: occupancy starvation / agent-scope
// coherence serialization). Total is 62us harness wall + ~25us here.
__global__ __launch_bounds__(256) void scan_kernel(const float* __restrict__ feat,
                                                   const float* __restrict__ pts_src,
                                                   const float* __restrict__ pts_dst,
                                                   const int* __restrict__ hptr,
                                                   const int* __restrict__ wptr,
                                                   float* __restrict__ psum,
                                                   unsigned int* __restrict__ pcnt) {
    __shared__ unsigned int wq[4][WQ_CAP];               // per-wave hit queues
    __shared__ unsigned int wqc[4];
    __shared__ float bsum[4];
    __shared__ unsigned int bcnt[4];
    const int pair  = blockIdx.x >> 7;                   // / (NT*MSPLIT)
    const int tile  = (blockIdx.x >> 1) & (NT - 1);
    const int mhalf = blockIdx.x & 1;
    const int mbase = mhalf * MLEN;
    const int i = pair >> 2;
    const int j = pair & 3;
    const float sx = ((float)(*wptr) - 1.0f) * 0.5f;
    const float sy = ((float)(*hptr) - 1.0f) * 0.5f;

    const int wave = threadIdx.x >> 6;
    const int lane = threadIdx.x & 63;
    if (lane == 0) wqc[wave] = 0u;                       // same-wave order: no barrier

    const int nbase = tile * TILE_N + wave * NPW;
    float psx[NPW], psy[NPW];
#pragma unroll
    for (int k = 0; k < NPW; ++k) {
        psx[k] = fmaf(pts_src[(size_t)(i * NN + nbase + k) * 2 + 0], sx, sx);
        psy[k] = fmaf(pts_src[(size_t)(i * NN + nbase + k) * 2 + 1], sy, sy);
    }

    // lane's view of this block's m-half: float4 = 2 raw points
    const float4* pd = (const float4*)(pts_dst + (size_t)pair * NN * 2 + (size_t)mbase * 2);

    float4 q = pd[lane];                                 // prefetch chunk 0
#pragma unroll
    for (int c = 0; c < MCH; ++c) {
        float4 qn;
        if (c + 1 < MCH) qn = pd[(c + 1) * 64 + lane];   // prefetch next
        const float qx0 = fmaf(q.x, sx, sx), qy0 = fmaf(q.y, sy, sy);
        const float qx1 = fmaf(q.z, sx, sx), qy1 = fmaf(q.w, sy, sy);
        float mn = 1e30f;
#pragma unroll
        for (int k = 0; k < NPW; ++k) {                  // d0/d1 transient (low VGPR)
            const float ax = psx[k] - qx0, ay = psy[k] - qy0;
            const float bx = psx[k] - qx1, by = psy[k] - qy1;
            mn = fminf(mn, fminf(fmaf(ax, ax, ay * ay), fmaf(bx, bx, by * by)));
        }
        if (__ballot(mn <= 64.0f)) {                     // rare slow path: recompute
            const unsigned int m2 = (unsigned int)(mbase + c * 128 + 2 * lane);
#pragma unroll
            for (int k = 0; k < NPW; ++k) {
                const float ax = psx[k] - qx0, ay = psy[k] - qy0;
                const float bx = psx[k] - qx1, by = psy[k] - qy1;
                const float d0 = fmaf(ax, ax, ay * ay);
                const float d1 = fmaf(bx, bx, by * by);
                if (fminf(d0, d1) <= 64.0f) {            // per-k early-out
                    if (d0 <= 64.0f) {
                        const unsigned int slot = atomicAdd(&wqc[wave], 1u);
                        if (slot < WQ_CAP) wq[wave][slot] = ((unsigned int)k << 11) | m2;
                    }
                    if (d1 <= 64.0f) {
                        const unsigned int slot = atomicAdd(&wqc[wave], 1u);
                        if (slot < WQ_CAP) wq[wave][slot] = ((unsigned int)k << 11) | (m2 + 1u);
                    }
                }
            }
        }
        q = qn;
    }

    // ---- tail: 16 hits at a time, 4 lanes/hit; dot + both norms fused ----
    const unsigned int hc = min(wqc[wave], (unsigned int)WQ_CAP);
    const int g = lane >> 2, sub = lane & 3;
    float lsum = 0.0f;
    for (unsigned int h0 = 0; h0 < hc; h0 += 16) {
        const unsigned int hid = h0 + (unsigned int)g;
        const bool valid = hid < hc;
        float dd = 0.0f, aa = 0.0f, bb = 0.0f;
        if (valid) {
            const unsigned int rec = wq[wave][hid];
            const int m = (int)(rec & 2047u);
            const int n = nbase + (int)(rec >> 11);
            const float4* pa = (const float4*)(feat + (size_t)(j * NN + n) * DD);
            const float4* pb = (const float4*)(feat + (size_t)(i * NN + m) * DD);
#pragma unroll
            for (int t = 0; t < 16; ++t) {
                const float4 a = pa[t * 4 + sub];
                const float4 b = pb[t * 4 + sub];
                dd = fmaf(a.x, b.x, fmaf(a.y, b.y, fmaf(a.z, b.z, fmaf(a.w, b.w, dd))));
                aa = fmaf(a.x, a.x, fmaf(a.y, a.y, fmaf(a.z, a.z, fmaf(a.w, a.w, aa))));
                bb = fmaf(b.x, b.x, fmaf(b.y, b.y, fmaf(b.z, b.z, fmaf(b.w, b.w, bb))));
            }
        }
        dd += __shfl_xor(dd, 1, 64);  aa += __shfl_xor(aa, 1, 64);  bb += __shfl_xor(bb, 1, 64);
        dd += __shfl_xor(dd, 2, 64);  aa += __shfl_xor(aa, 2, 64);  bb += __shfl_xor(bb, 2, 64);
        if (valid && sub == 0) {
            const float p = aa * bb;                     // (|fa|*|fb|)^2 >> eps^2
            float r = rsqrtf(p);
            r = r * (1.5f - 0.5f * p * r * r);           // one Newton step
            lsum += 1.0f - dd * r;
        }
    }
#pragma unroll
    for (int off = 32; off >= 1; off >>= 1) lsum += __shfl_xor(lsum, off, 64);

    // ---- block reduction -> private slot (plain stores, no atomics) ----
    if (lane == 0) { bsum[wave] = lsum; bcnt[wave] = hc; }
    __syncthreads();
    if (threadIdx.x == 0) {
        psum[blockIdx.x] = bsum[0] + bsum[1] + bsum[2] + bsum[3];
        pcnt[blockIdx.x] = bcnt[0] + bcnt[1] + bcnt[2] + bcnt[3];
    }
}

// Kernel 2: reduce the 2048 block partials. One block.
__global__ __launch_bounds__(256) void finalize_kernel(const float* __restrict__ psum,
                                                       const unsigned int* __restrict__ pcnt,
                                                       float* __restrict__ out) {
    float s = 0.0f;
    float c = 0.0f;                                      // hits < 2^24, exact in f32
    for (int t = threadIdx.x; t < NBLK; t += 256) {
        s += psum[t];
        c += (float)pcnt[t];
    }
#pragma unroll
    for (int off = 32; off >= 1; off >>= 1) {
        s += __shfl_xor(s, off, 64);
        c += __shfl_xor(c, off, 64);
    }
    __shared__ float ss[4], cc[4];
    const int wave = threadIdx.x >> 6;
    const int lane = threadIdx.x & 63;
    if (lane == 0) { ss[wave] = s; cc[wave] = c; }
    __syncthreads();
    if (threadIdx.x == 0) {
        const float S = ss[0] + ss[1] + ss[2] + ss[3];
        const float C = cc[0] + cc[1] + cc[2] + cc[3];
        out[0] = S / fmaxf(C, 1.0f);                     // max(cnt, 1)
    }
}

extern "C" void kernel_launch(void* const* d_in, const int* in_sizes, int n_in,
                              void* d_out, int out_size, void* d_ws, size_t ws_size,
                              hipStream_t stream) {
    const float* feat    = (const float*)d_in[0];   // [B,N,D] f32
    const float* pts_src = (const float*)d_in[1];   // [B,N,2] f32
    const float* pts_dst = (const float*)d_in[2];   // [B,B,N,2] f32
    // d_in[3] = invis_idx — unused by the reference
    const int* hptr = (const int*)d_in[4];          // height (scalar)
    const int* wptr = (const int*)d_in[5];          // width  (scalar)
    float* out = (float*)d_out;

    float*        psum  = (float*)d_ws;                          // 8 KB
    unsigned int* pcnt  = (unsigned int*)((char*)d_ws + 8192);   // 8 KB

    scan_kernel<<<NBLK, 256, 0, stream>>>(feat, pts_src, pts_dst,
                                          hptr, wptr, psum, pcnt);
    finalize_kernel<<<1, 256, 0, stream>>>(psum, pcnt, out);
}